// Round 22
// baseline (337.272 us; speedup 1.0000x reference)
//
#include <hip/hip_runtime.h>
#include <hip/hip_bf16.h>

#define L_SEQ 2048
#define HIDN  2048
#define NH    32
#define BATCHN 4
#define CHUNK 64

using bf16x8 = __attribute__((ext_vector_type(8))) short;
using f32x4  = __attribute__((ext_vector_type(4))) float;

__device__ __forceinline__ unsigned short f2bf(float f) {
  union { float f; unsigned u; } v; v.f = f;
  unsigned r = v.u + 0x7fffu + ((v.u >> 16) & 1u);
  return (unsigned short)(r >> 16);
}

__device__ __forceinline__ float bf2f(unsigned short u) {
  unsigned v = ((unsigned)u) << 16;
  return __builtin_bit_cast(float, v);
}

__device__ __forceinline__ void gl_lds16(const void* g, void* l) {
  __builtin_amdgcn_global_load_lds(
      (const __attribute__((address_space(1))) unsigned int*)g,
      (__attribute__((address_space(3))) unsigned int*)l, 16, 0, 0);
}

template <int CTRL>
__device__ __forceinline__ float qperm(float x) {
  int xi = __builtin_bit_cast(int, x);
  int yi = __builtin_amdgcn_update_dpp(0, xi, CTRL, 0xF, 0xF, true);
  return __builtin_bit_cast(float, yi);
}

#define BARRIER() do { asm volatile("" ::: "memory"); \
  __builtin_amdgcn_s_barrier(); asm volatile("" ::: "memory"); } while (0)

// ---- merged prep: x->bf16, gw->bf16, ow*nw->bf16, Cw->bf16, conv-w transform -
__global__ __launch_bounds__(256) void prep_k(const float* __restrict__ x,
                                              const float* __restrict__ gw,
                                              const float* __restrict__ ow,
                                              const float* __restrict__ nw,
                                              const float* __restrict__ Cw,
                                              const float* __restrict__ cw,
                                              unsigned short* __restrict__ xb,
                                              unsigned short* __restrict__ gwb,
                                              unsigned short* __restrict__ owb,
                                              unsigned short* __restrict__ cwb,
                                              unsigned short* __restrict__ wret) {
  const int U0 = 4194304, U1 = U0 + 1048576, U2 = U1 + 1048576;
  const int U3 = U2 + 32768, U4 = U3 + 524288;
  for (int i = blockIdx.x * 256 + threadIdx.x; i < U4; i += gridDim.x * 256) {
    if (i < U0) {
      float4 v = *(const float4*)&x[(size_t)i * 4];
      ushort4 o = { f2bf(v.x), f2bf(v.y), f2bf(v.z), f2bf(v.w) };
      *(ushort4*)&xb[(size_t)i * 4] = o;
    } else if (i < U1) {
      int j = i - U0;
      float4 v = *(const float4*)&gw[(size_t)j * 4];
      ushort4 o = { f2bf(v.x), f2bf(v.y), f2bf(v.z), f2bf(v.w) };
      *(ushort4*)&gwb[(size_t)j * 4] = o;
    } else if (i < U2) {
      int j = i - U1;
      float4 v = *(const float4*)&ow[(size_t)j * 4];
      int k0 = (j * 4) & 2047;
      ushort4 o = { f2bf(v.x * nw[k0]), f2bf(v.y * nw[k0 + 1]),
                    f2bf(v.z * nw[k0 + 2]), f2bf(v.w * nw[k0 + 3]) };
      *(ushort4*)&owb[(size_t)j * 4] = o;
    } else if (i < U3) {
      int j = i - U2;
      float4 v = *(const float4*)&Cw[(size_t)j * 4];
      ushort4 o = { f2bf(v.x), f2bf(v.y), f2bf(v.z), f2bf(v.w) };
      *(ushort4*)&cwb[(size_t)j * 4] = o;
    } else {
      int idx = i - U3;
      int o = idx >> 8, q = idx & 255;
      int k = q >> 6, ii = q & 63;
      wret[idx] = f2bf(cw[o * 256 + ii * 4 + k]);
    }
  }
}

// ===== 256x256 tile, BK=64, 8-wave, K-quarter GEMM (out-proj). Barriers at
// ===== p0 AND p2 (after the vmcnt waits) close the cross-wave staging race.
__global__ __launch_bounds__(512, 2) void gemm256_out_k(const unsigned short* __restrict__ X,
                                                        const unsigned short* __restrict__ W,
                                                        const float* __restrict__ sums,
                                                        float* __restrict__ OUT,
                                                        int M, int N, int K) {
  __shared__ __align__(16) char smem[131072];
  const int tid = threadIdx.x, lane = tid & 63, w = tid >> 6;
  const int wm = w >> 2, wn = w & 3, fr = lane & 15, kg = lane >> 4;
  const int nbx = M >> 8, nby = N >> 8;
  const int nwg = nbx * nby, cpx = nwg >> 3;
  const int lin = blockIdx.x;
  const int swz = (lin & 7) * cpx + (lin >> 3);
  const int m0 = (swz % nbx) * 256, n0 = (swz / nbx) * 256;

  auto stageQ = [&](int buf, int quarter, int ktile) {
    const unsigned short* SRCp = (quarter & 1) ? W : X;
    const int base0 = (quarter & 1) ? n0 : m0;
    const int kofs = (ktile << 6) + ((quarter >> 1) << 5);
#pragma unroll
    for (int q2 = 0; q2 < 2; ++q2) {
      int s = q2 * 8192 + tid * 16;
      int r = s >> 6, cb = s & 63;
      int lcol = (cb ^ (((r >> 1) & 3) << 4)) >> 1;
      gl_lds16(&SRCp[(size_t)(base0 + r) * K + kofs + lcol],
               smem + buf * 65536 + quarter * 16384 + s);
    }
  };
  stageQ(0, 0, 0); stageQ(0, 1, 0); stageQ(0, 2, 0); stageQ(0, 3, 0);
  f32x4 acc[8][4] = {};
  int cur = 0;
  const int NT = K >> 6;
  for (int kt = 0; kt < NT; ++kt) {
#pragma unroll
    for (int p = 0; p < 4; ++p) {
      const int ks = p >> 1, mg = p & 1;
      if (p == 0) {
        asm volatile("s_waitcnt vmcnt(4)" ::: "memory");
        BARRIER();
        if (kt + 1 < NT) stageQ(cur ^ 1, 0, kt + 1);
      } else if (p == 1) {
        if (kt + 1 < NT) stageQ(cur ^ 1, 1, kt + 1);
      } else if (p == 2) {
        if (kt + 1 < NT) { asm volatile("s_waitcnt vmcnt(4)" ::: "memory"); }
        else             { asm volatile("s_waitcnt vmcnt(0)" ::: "memory"); }
        BARRIER();                         // all waves' khi visible
        if (kt + 1 < NT) stageQ(cur ^ 1, 2, kt + 1);
      } else {
        if (kt + 1 < NT) stageQ(cur ^ 1, 3, kt + 1);
      }
      const char* Ab = smem + cur * 65536 + ks * 32768;
      const char* Bb = Ab + 16384;
      bf16x8 af[4], bfr[4];
#pragma unroll
      for (int t = 0; t < 4; ++t) {
        const int Ra = wm * 128 + mg * 64 + t * 16 + fr;
        af[t] = *(const bf16x8*)(Ab + Ra * 64 + ((kg ^ ((Ra >> 1) & 3)) << 4));
        const int Rb = wn * 64 + t * 16 + fr;
        bfr[t] = *(const bf16x8*)(Bb + Rb * 64 + ((kg ^ ((Rb >> 1) & 3)) << 4));
      }
      asm volatile("s_waitcnt lgkmcnt(0)" ::: "memory");
      __builtin_amdgcn_sched_barrier(0);
      __builtin_amdgcn_s_setprio(1);
#pragma unroll
      for (int t = 0; t < 4; ++t)
#pragma unroll
        for (int nf = 0; nf < 4; ++nf)
          acc[mg * 4 + t][nf] = __builtin_amdgcn_mfma_f32_16x16x32_bf16(
              af[t], bfr[nf], acc[mg * 4 + t][nf], 0, 0, 0);
      __builtin_amdgcn_s_setprio(0);
    }
    cur ^= 1;
  }

#pragma unroll
  for (int mf = 0; mf < 8; ++mf)
#pragma unroll
    for (int nf = 0; nf < 4; ++nf) {
      const int col = n0 + wn * 64 + nf * 16 + fr;
#pragma unroll
      for (int r = 0; r < 4; ++r) {
        const int row = m0 + wm * 128 + mf * 16 + kg * 4 + r;
        float rsv = rsqrtf(sums[row] * (1.0f / HIDN) + 1e-6f);
        OUT[(size_t)row * N + col] = acc[mf][nf][r] * rsv;
      }
    }
}

// --- grouped causal conv as MFMA GEMM; epilogue: (Bc+bias)*dt -> dBt[row][l] --
__global__ __launch_bounds__(256) void conv_k(const unsigned short* __restrict__ xb,
                                              const unsigned short* __restrict__ wreT,
                                              const float* __restrict__ conv_b,
                                              const float* __restrict__ dt,
                                              float* __restrict__ dBt) {
  __shared__ __align__(16) unsigned short x_lds[67 * 64];
  const int l0 = blockIdx.x * 64, g = blockIdx.y, b = blockIdx.z;
  const int tid = threadIdx.x, lane = tid & 63, wid = tid >> 6;
  {
    const int r = tid >> 3, ch = (tid & 7) * 8;
#pragma unroll
    for (int pass = 0; pass < 3; ++pass) {
      int rr = r + pass * 32;
      if (rr < 67) {
        int lg = l0 - 3 + rr;
        bf16x8 v = {};
        if (lg >= 0) v = *(const bf16x8*)&xb[(size_t)(b * L_SEQ + lg) * HIDN + g * 64 + ch];
        *(bf16x8*)&x_lds[rr * 64 + ch] = v;
      }
    }
  }
  __syncthreads();
  const int fr = lane & 15, kg = lane >> 4, wm = wid;
  f32x4 acc[4] = {};
#pragma unroll
  for (int ks = 0; ks < 8; ++ks) {
    bf16x8 a = *(const bf16x8*)&x_lds[(wm * 16 + fr + (ks >> 1)) * 64 + (ks & 1) * 32 + kg * 8];
#pragma unroll
    for (int nt = 0; nt < 4; ++nt) {
      bf16x8 bq = *(const bf16x8*)&wreT[(size_t)(g * 64 + nt * 16 + fr) * 256 + ks * 32 + kg * 8];
      acc[nt] = __builtin_amdgcn_mfma_f32_16x16x32_bf16(a, bq, acc[nt], 0, 0, 0);
    }
  }
  const int lgb = l0 + wm * 16 + kg * 4;
  const float4 dt4 = *(const float4*)&dt[b * L_SEQ + lgb];
#pragma unroll
  for (int nt = 0; nt < 4; ++nt) {
    const int o = nt * 16 + fr;
    const float bias = conv_b[g * 64 + o];
    float4 vv;
    vv.x = (acc[nt][0] + bias) * dt4.x;
    vv.y = (acc[nt][1] + bias) * dt4.y;
    vv.z = (acc[nt][2] + bias) * dt4.z;
    vv.w = (acc[nt][3] + bias) * dt4.w;
    *(float4*)&dBt[((size_t)(b * NH + g) * 64 + o) * L_SEQ + lgb] = vv;
  }
}

// ==== FUSED v3: blocks 0..63 = scan, two independent waves/block (private
// ==== 63.5KB LDS halves); blocks 64..575 = gate GEMM 256x128 tiles with
// ==== p0+p2 barriers (race-free counted-vmcnt), silu -> bf16.
__global__ __launch_bounds__(512, 1) void scan_gate_k(const float* __restrict__ dBt,
                                                      const float* __restrict__ Aw,
                                                      const float* __restrict__ dt,
                                                      unsigned short* __restrict__ states,
                                                      const unsigned short* __restrict__ X,
                                                      const unsigned short* __restrict__ W,
                                                      unsigned short* __restrict__ GOUT) {
  __shared__ __align__(16) char smem[131072];
  if (blockIdx.x >= 64) {
    // -------- gate GEMM: 256(M) x 128(N) tiles, K=2048; 512 tiles -----------
    const int tid = threadIdx.x, lane = tid & 63, w = tid >> 6;
    const int wm = w >> 1, wn = w & 1, fr = lane & 15, kg = lane >> 4;
    const int gb = blockIdx.x - 64;              // 0..511
    const int swz = (gb & 7) * 64 + (gb >> 3);   // XCD-bijective (512 % 8 == 0)
    const int m0 = (swz & 31) * 256, n0 = (swz >> 5) * 128;

    // quarters: [A-klo 16K | B-klo 8K | A-khi 16K | B-khi 8K]; dbuf stride 48K
    auto stageQ = [&](int buf, int quarter, int ktile) {
      const unsigned short* SRCp = (quarter & 1) ? W : X;
      const int base0 = (quarter & 1) ? n0 : m0;
      const int kofs = (ktile << 6) + ((quarter >> 1) << 5);
      const int qoff = (quarter & 1) ? (16384 + (quarter >> 1) * 24576)
                                     : ((quarter >> 1) * 24576);
      {
        int s = tid * 16;
        int r = s >> 6, cb = s & 63;
        int lcol = (cb ^ (((r >> 1) & 3) << 4)) >> 1;
        gl_lds16(&SRCp[(size_t)(base0 + r) * 2048 + kofs + lcol],
                 smem + buf * 49152 + qoff + s);
      }
      if (!(quarter & 1)) {     // A quarters are 16KB = 2 units
        int s = 8192 + tid * 16;
        int r = s >> 6, cb = s & 63;
        int lcol = (cb ^ (((r >> 1) & 3) << 4)) >> 1;
        gl_lds16(&SRCp[(size_t)(base0 + r) * 2048 + kofs + lcol],
                 smem + buf * 49152 + qoff + s);
      }
    };
    stageQ(0, 0, 0); stageQ(0, 1, 0); stageQ(0, 2, 0); stageQ(0, 3, 0);
    f32x4 acc[4][4] = {};
    int cur = 0;
    for (int kt = 0; kt < 32; ++kt) {
#pragma unroll
      for (int p = 0; p < 4; ++p) {
        const int ks = p >> 1, mg = p & 1;
        if (p == 0) {
          asm volatile("s_waitcnt vmcnt(3)" ::: "memory");
          BARRIER();
          if (kt + 1 < 32) stageQ(cur ^ 1, 0, kt + 1);
        } else if (p == 1) {
          if (kt + 1 < 32) stageQ(cur ^ 1, 1, kt + 1);
        } else if (p == 2) {
          if (kt + 1 < 32) { asm volatile("s_waitcnt vmcnt(3)" ::: "memory"); }
          else             { asm volatile("s_waitcnt vmcnt(0)" ::: "memory"); }
          BARRIER();                       // all waves' khi visible (race fix)
          if (kt + 1 < 32) stageQ(cur ^ 1, 2, kt + 1);
        } else {
          if (kt + 1 < 32) stageQ(cur ^ 1, 3, kt + 1);
        }
        const char* Ab = smem + cur * 49152 + ks * 24576;
        const char* Bb = smem + cur * 49152 + 16384 + ks * 24576;
        bf16x8 af[2], bfr[4];
#pragma unroll
        for (int t = 0; t < 2; ++t) {
          const int Ra = wm * 64 + mg * 32 + t * 16 + fr;
          af[t] = *(const bf16x8*)(Ab + Ra * 64 + ((kg ^ ((Ra >> 1) & 3)) << 4));
        }
#pragma unroll
        for (int nf = 0; nf < 4; ++nf) {
          const int Rb = wn * 64 + nf * 16 + fr;
          bfr[nf] = *(const bf16x8*)(Bb + Rb * 64 + ((kg ^ ((Rb >> 1) & 3)) << 4));
        }
        asm volatile("s_waitcnt lgkmcnt(0)" ::: "memory");
        __builtin_amdgcn_sched_barrier(0);
        __builtin_amdgcn_s_setprio(1);
#pragma unroll
        for (int t = 0; t < 2; ++t)
#pragma unroll
          for (int nf = 0; nf < 4; ++nf)
            acc[mg * 2 + t][nf] = __builtin_amdgcn_mfma_f32_16x16x32_bf16(
                af[t], bfr[nf], acc[mg * 2 + t][nf], 0, 0, 0);
        __builtin_amdgcn_s_setprio(0);
      }
      cur ^= 1;
    }
#pragma unroll
    for (int mf = 0; mf < 4; ++mf)
#pragma unroll
      for (int nf = 0; nf < 4; ++nf) {
        const int col = n0 + wn * 64 + nf * 16 + fr;
#pragma unroll
        for (int r = 0; r < 4; ++r) {
          const int row = m0 + wm * 64 + mf * 16 + kg * 4 + r;
          float v = acc[mf][nf][r];
          v = v / (1.f + __expf(-v));
          GOUT[(size_t)row * 2048 + col] = f2bf(v);
        }
      }
    return;
  }
  // ------------- scan: 2 independent waves, bid = blk*2 + wave --------------
  if (threadIdx.x >= 128) return;
  const int wv = threadIdx.x >> 6;
  const int bid = blockIdx.x * 2 + wv;   // b*32 + h
  const int h = bid & 31, b = bid >> 5;
  const int lane = threadIdx.x & 63;
  const int fr = lane & 15, kg = lane >> 4;

  char* base = smem + wv * 63488;   // per-wave private LDS half
  char* sp = base;                  // s-pairs [CHUNK] stride 176B   (11264 B)
  char* xT = base + 11264;          // xT [CHUNK] stride 304B        (19456 B)
  char* db = base + 30720;          // Dv staging: 2 bufs x 16KB

  bf16x8 afr[4][2];
  {
    const float* Ah = Aw + (size_t)h * 64 * 64;
#pragma unroll
    for (int mb = 0; mb < 4; ++mb)
#pragma unroll
      for (int kt = 0; kt < 2; ++kt) {
        const float* p = &Ah[(size_t)(mb * 16 + fr) * 64 + kt * 32 + kg * 8];
        float4 v0 = *(const float4*)p;
        float4 v1 = *(const float4*)(p + 4);
        bf16x8 f;
        f[0] = (short)f2bf(v0.x); f[1] = (short)f2bf(v0.y);
        f[2] = (short)f2bf(v0.z); f[3] = (short)f2bf(v0.w);
        f[4] = (short)f2bf(v1.x); f[5] = (short)f2bf(v1.y);
        f[6] = (short)f2bf(v1.z); f[7] = (short)f2bf(v1.w);
        afr[mb][kt] = f;
      }
  }

  const float* dBp = dBt + (size_t)(bid * 64 + lane) * L_SEQ;   // own row
  unsigned short* stbase = states + (size_t)bid * L_SEQ * 64;
  const float* dtp = dt + b * L_SEQ;
  const int spw = (lane >> 1) * 4;

  auto pfDv = [&](int buf, int c) {
#pragma unroll
    for (int q = 0; q < 16; ++q)
      gl_lds16(&dBp[c * CHUNK + q * 4], db + buf * 16384 + q * 1024);
  };
  pfDv(0, 0);

  float scs = 0.f;
  for (int c = 0; c < L_SEQ / CHUNK; ++c) {
    const int l0 = c * CHUNK;
    const int buf = c & 1;
    if (c == 0) { asm volatile("s_waitcnt vmcnt(0)" ::: "memory"); }
    else        { asm volatile("s_waitcnt vmcnt(8)" ::: "memory"); }
    float Dv[CHUNK];
#pragma unroll
    for (int q = 0; q < 16; ++q) {
      f32x4 v = *(const f32x4*)(db + buf * 16384 + q * 1024 + lane * 16);
      Dv[q * 4] = v[0]; Dv[q * 4 + 1] = v[1]; Dv[q * 4 + 2] = v[2]; Dv[q * 4 + 3] = v[3];
    }
    float dtq[4];
#pragma unroll
    for (int tb = 0; tb < 4; ++tb) dtq[tb] = dtp[l0 + tb * 16 + fr];
    if (c + 1 < L_SEQ / CHUNK) pfDv(buf ^ 1, c + 1);

    // ---- pass 1 (E=1): write s-pair (state BEFORE step l), then s += Dv ----
    {
      float s = scs;
#pragma unroll
      for (int l = 0; l < CHUNK; ++l) {
        float sn = qperm<0xB1>(s);
        float lo = (lane & 1) ? sn : s;
        float hi = (lane & 1) ? s : sn;
        unsigned pw;
        asm("v_cvt_pk_bf16_f32 %0, %1, %2" : "=v"(pw) : "v"(lo), "v"(hi));
        *(unsigned*)(sp + l * 176 + spw) = pw;
        s = s + Dv[l];
      }
    }
    asm volatile("" ::: "memory");
    // ---- batched matvec: X[m][t] = A_w · S, scaled by dt ----
    {
      bf16x8 bf[4][2];
#pragma unroll
      for (int tb = 0; tb < 4; ++tb)
#pragma unroll
        for (int kt = 0; kt < 2; ++kt)
          bf[tb][kt] = *(const bf16x8*)(sp + (tb * 16 + fr) * 176 + (kt * 16 + kg * 4) * 4);
      f32x4 acc2[4][4];
#pragma unroll
      for (int mb = 0; mb < 4; ++mb)
#pragma unroll
        for (int tb = 0; tb < 4; ++tb) {
          f32x4 z = {0.f, 0.f, 0.f, 0.f};
          f32x4 t0 = __builtin_amdgcn_mfma_f32_16x16x32_bf16(afr[mb][0], bf[tb][0], z, 0, 0, 0);
          acc2[mb][tb] = __builtin_amdgcn_mfma_f32_16x16x32_bf16(afr[mb][1], bf[tb][1], t0, 0, 0, 0);
        }
#pragma unroll
      for (int mb = 0; mb < 4; ++mb)
#pragma unroll
        for (int tb = 0; tb < 4; ++tb) {
          f32x4 v = acc2[mb][tb];
          v[0] *= dtq[tb]; v[1] *= dtq[tb]; v[2] *= dtq[tb]; v[3] *= dtq[tb];
          *(f32x4*)(xT + (tb * 16 + fr) * 304 + (mb * 16 + kg * 4) * 4) = v;
        }
    }
    asm volatile("" ::: "memory");
    // ---- final pass: E inline; pack exact states to sp; bulk-store chunk ----
    {
      float s = scs;
#pragma unroll
      for (int gq = 0; gq < CHUNK / 8; ++gq) {
        float xs[8];
#pragma unroll
        for (int j = 0; j < 8; ++j)
          xs[j] = *(const float*)(xT + (gq * 8 + j) * 304 + lane * 4);
#pragma unroll
        for (int j = 0; j < 8; ++j) {
          const int l = gq * 8 + j;
          float xv = xs[j];
          float E = __builtin_fmaf(xv * xv, 0.5f, 1.0f + xv);
          s = __builtin_fmaf(E, s, Dv[l]);
          float sn = qperm<0xB1>(s);
          float lo = (lane & 1) ? sn : s;
          float hi = (lane & 1) ? s : sn;
          unsigned pw;
          asm("v_cvt_pk_bf16_f32 %0, %1, %2" : "=v"(pw) : "v"(lo), "v"(hi));
          *(unsigned*)(sp + l * 176 + spw) = pw;
        }
      }
      scs = s;
    }
    asm volatile("" ::: "memory");
#pragma unroll
    for (int j2 = 0; j2 < 8; ++j2) {
      const int g0 = j2 * 1024 + lane * 16;
      const int lrow = g0 >> 7, cbyte = g0 & 127;
      bf16x8 vv = *(const bf16x8*)(sp + lrow * 176 + cbyte);
      *(bf16x8*)&stbase[(size_t)l0 * 64 + (g0 >> 1)] = vv;
    }
  }
}

// -- C proj + x*D + silu(gate); LDS-staged coalesced bf16 stores + row sums ----
__global__ __launch_bounds__(256) void proj_k(const unsigned short* __restrict__ st,
                                              const unsigned short* __restrict__ cwb,
                                              const unsigned short* __restrict__ xbp,
                                              const float* __restrict__ Dp,
                                              const unsigned short* __restrict__ gsb,
                                              unsigned short* __restrict__ hsb,
                                              float* __restrict__ sums) {
  __shared__ __align__(16) unsigned short hls[64 * 72];   // padded stride 72
  const int l0 = blockIdx.x * 64, h = blockIdx.y, b = blockIdx.z;
  const int tid = threadIdx.x, lane = tid & 63, wid = tid >> 6;
  const int fr = lane & 15, kg = lane >> 4, wm = wid;
  f32x4 acc[4] = {};
#pragma unroll
  for (int ks = 0; ks < 2; ++ks) {
    bf16x8 a = *(const bf16x8*)&st[((size_t)(b * NH + h) * L_SEQ + l0 + wm * 16 + fr) * 64 + ks * 32 + kg * 8];
#pragma unroll
    for (int nt = 0; nt < 4; ++nt) {
      bf16x8 bq = *(const bf16x8*)&cwb[(size_t)(h * 64 + nt * 16 + fr) * 64 + ks * 32 + kg * 8];
      acc[nt] = __builtin_amdgcn_mfma_f32_16x16x32_bf16(a, bq, acc[nt], 0, 0, 0);
    }
  }
  const float Dh = Dp[h];
#pragma unroll
  for (int r = 0; r < 4; ++r) {
    const int lg = l0 + wm * 16 + kg * 4 + r;
    float sq = 0.f;
#pragma unroll
    for (int nt = 0; nt < 4; ++nt) {
      const int ccol = h * 64 + nt * 16 + fr;
      const size_t idx = (size_t)(b * L_SEQ + lg) * HIDN + ccol;
      float v = acc[nt][r] + bf2f(xbp[idx]) * Dh;
      float hv = v * bf2f(gsb[idx]);
      hls[(wm * 16 + kg * 4 + r) * 72 + nt * 16 + fr] = f2bf(hv);
      sq += hv * hv;
    }
    sq += __shfl_xor(sq, 1);
    sq += __shfl_xor(sq, 2);
    sq += __shfl_xor(sq, 4);
    sq += __shfl_xor(sq, 8);
    if (fr == 0) atomicAdd(&sums[b * L_SEQ + lg], sq);
  }
  __syncthreads();
#pragma unroll
  for (int it = 0; it < 2; ++it) {
    int unit = tid + it * 256;               // 512 units of 16B
    int row = unit >> 3, seg = unit & 7;
    bf16x8 vv = *(const bf16x8*)&hls[row * 72 + seg * 8];
    *(bf16x8*)&hsb[(size_t)(b * L_SEQ + l0 + row) * HIDN + h * 64 + seg * 8] = vv;
  }
}

extern "C" void kernel_launch(void* const* d_in, const int* in_sizes, int n_in,
                              void* d_out, int out_size, void* d_ws, size_t ws_size,
                              hipStream_t stream) {
  const float* x  = (const float*)d_in[0];
  const float* dt = (const float*)d_in[1];
  const float* gw = (const float*)d_in[2];
  const float* Aw = (const float*)d_in[3];
  const float* cw = (const float*)d_in[4];
  const float* cb = (const float*)d_in[5];
  const float* Cw = (const float*)d_in[6];
  const float* Dp = (const float*)d_in[7];
  const float* nw = (const float*)d_in[8];
  const float* ow = (const float*)d_in[9];
  float* out = (float*)d_out;

  char* w = (char*)d_ws;
  unsigned short* xb   = (unsigned short*)(w);                // 32MB
  unsigned short* gwb  = (unsigned short*)(w + 33554432);     // 8MB
  unsigned short* owb  = (unsigned short*)(w + 41943040);     // 8MB (ow*nw)
  unsigned short* wret = (unsigned short*)(w + 50331648);     // 1MB
  unsigned short* cwb  = (unsigned short*)(w + 51380224);     // 256KB
  float*          sums = (float*)(w + 51642368);              // 32KB (row sums)
  float*          dBt  = (float*)(w + 52428800);              // 64MB
  unsigned short* hsb  = (unsigned short*)(w + 52428800);     // overlay (after scan)
  unsigned short* stb  = (unsigned short*)(w + 119537664);    // 32MB
  unsigned short* gsb  = (unsigned short*)d_out;              // gate bf16, 32MB
  if (ws_size < 153092096) return;

  hipMemsetAsync(sums, 0, 8192 * sizeof(float), stream);
  prep_k<<<2048, 256, 0, stream>>>(x, gw, ow, nw, Cw, cw, xb, gwb, owb, cwb, wret);
  conv_k<<<dim3(32, 32, 4), 256, 0, stream>>>(xb, wret, cb, dt, dBt);
  // FUSED v3: scan (blocks 0..63, 2 waves each) || gate GEMM 256x128 tiles
  scan_gate_k<<<576, 512, 0, stream>>>(dBt, Aw, dt, stb, xb, gwb, gsb);
  proj_k<<<dim3(32, 32, 4), 256, 0, stream>>>(stb, cwb, xb, Dp, gsb, hsb, sums);
  gemm256_out_k<<<256, 512, 0, stream>>>(hsb, owb, sums, out, 8192, 2048, 2048);
}

// Round 23
// 326.754 us; speedup vs baseline: 1.0322x; 1.0322x over previous
//
#include <hip/hip_runtime.h>
#include <hip/hip_bf16.h>

#define L_SEQ 2048
#define HIDN  2048
#define NH    32
#define BATCHN 4
#define CHUNK 64

using bf16x8 = __attribute__((ext_vector_type(8))) short;
using f32x4  = __attribute__((ext_vector_type(4))) float;

__device__ __forceinline__ unsigned short f2bf(float f) {
  union { float f; unsigned u; } v; v.f = f;
  unsigned r = v.u + 0x7fffu + ((v.u >> 16) & 1u);
  return (unsigned short)(r >> 16);
}

__device__ __forceinline__ float bf2f(unsigned short u) {
  unsigned v = ((unsigned)u) << 16;
  return __builtin_bit_cast(float, v);
}

__device__ __forceinline__ void gl_lds16(const void* g, void* l) {
  __builtin_amdgcn_global_load_lds(
      (const __attribute__((address_space(1))) unsigned int*)g,
      (__attribute__((address_space(3))) unsigned int*)l, 16, 0, 0);
}

template <int CTRL>
__device__ __forceinline__ float qperm(float x) {
  int xi = __builtin_bit_cast(int, x);
  int yi = __builtin_amdgcn_update_dpp(0, xi, CTRL, 0xF, 0xF, true);
  return __builtin_bit_cast(float, yi);
}

#define BARRIER() do { asm volatile("" ::: "memory"); \
  __builtin_amdgcn_s_barrier(); asm volatile("" ::: "memory"); } while (0)

// ---- merged prep: x->bf16, gw->bf16, ow*nw->bf16, Cw->bf16, conv-w transform -
__global__ __launch_bounds__(256) void prep_k(const float* __restrict__ x,
                                              const float* __restrict__ gw,
                                              const float* __restrict__ ow,
                                              const float* __restrict__ nw,
                                              const float* __restrict__ Cw,
                                              const float* __restrict__ cw,
                                              unsigned short* __restrict__ xb,
                                              unsigned short* __restrict__ gwb,
                                              unsigned short* __restrict__ owb,
                                              unsigned short* __restrict__ cwb,
                                              unsigned short* __restrict__ wret) {
  const int U0 = 4194304, U1 = U0 + 1048576, U2 = U1 + 1048576;
  const int U3 = U2 + 32768, U4 = U3 + 524288;
  for (int i = blockIdx.x * 256 + threadIdx.x; i < U4; i += gridDim.x * 256) {
    if (i < U0) {
      float4 v = *(const float4*)&x[(size_t)i * 4];
      ushort4 o = { f2bf(v.x), f2bf(v.y), f2bf(v.z), f2bf(v.w) };
      *(ushort4*)&xb[(size_t)i * 4] = o;
    } else if (i < U1) {
      int j = i - U0;
      float4 v = *(const float4*)&gw[(size_t)j * 4];
      ushort4 o = { f2bf(v.x), f2bf(v.y), f2bf(v.z), f2bf(v.w) };
      *(ushort4*)&gwb[(size_t)j * 4] = o;
    } else if (i < U2) {
      int j = i - U1;
      float4 v = *(const float4*)&ow[(size_t)j * 4];
      int k0 = (j * 4) & 2047;
      ushort4 o = { f2bf(v.x * nw[k0]), f2bf(v.y * nw[k0 + 1]),
                    f2bf(v.z * nw[k0 + 2]), f2bf(v.w * nw[k0 + 3]) };
      *(ushort4*)&owb[(size_t)j * 4] = o;
    } else if (i < U3) {
      int j = i - U2;
      float4 v = *(const float4*)&Cw[(size_t)j * 4];
      ushort4 o = { f2bf(v.x), f2bf(v.y), f2bf(v.z), f2bf(v.w) };
      *(ushort4*)&cwb[(size_t)j * 4] = o;
    } else {
      int idx = i - U3;
      int o = idx >> 8, q = idx & 255;
      int k = q >> 6, ii = q & 63;
      wret[idx] = f2bf(cw[o * 256 + ii * 4 + k]);
    }
  }
}

// ===== 256x256 tile, BK=64, 8-wave, double-buffered 4-phase pipelined GEMM ====
// out-projection; epilogue: v * rsqrt(mean(hs^2)+eps) from row sums buffer.
__global__ __launch_bounds__(512, 2) void gemm256_out_k(const unsigned short* __restrict__ X,
                                                        const unsigned short* __restrict__ W,
                                                        const float* __restrict__ sums,
                                                        float* __restrict__ OUT,
                                                        int M, int N, int K) {
  __shared__ __align__(16) char smem[131072];
  const int tid = threadIdx.x, lane = tid & 63, w = tid >> 6;
  const int wm = w >> 2, wn = w & 3, fr = lane & 15, kg = lane >> 4;
  const int nbx = M >> 8, nby = N >> 8;
  const int nwg = nbx * nby, cpx = nwg >> 3;
  const int lin = blockIdx.x;
  const int swz = (lin & 7) * cpx + (lin >> 3);
  const int m0 = (swz % nbx) * 256, n0 = (swz / nbx) * 256;
  const int twistL = (fr & 7) << 4;

  auto stageA = [&](int buf, int half, int kq) {
#pragma unroll
    for (int q = 0; q < 2; ++q) {
      int s = q * 8192 + tid * 16;
      int r = s >> 7, cb = s & 127;
      const void* src = &X[(size_t)(m0 + half * 128 + r) * K + kq + ((cb ^ ((r & 7) << 4)) >> 1)];
      void* dst = smem + buf * 65536 + half * 16384 + q * 8192 + w * 1024;
      gl_lds16(src, dst);
    }
  };
  auto stageB = [&](int buf, int half, int kq) {
#pragma unroll
    for (int q = 0; q < 2; ++q) {
      int s = q * 8192 + tid * 16;
      int r = s >> 7, cb = s & 127;
      const void* src = &W[(size_t)(n0 + half * 128 + r) * K + kq + ((cb ^ ((r & 7) << 4)) >> 1)];
      void* dst = smem + buf * 65536 + 32768 + half * 16384 + q * 8192 + w * 1024;
      gl_lds16(src, dst);
    }
  };

  stageA(0, 0, 0); stageA(0, 1, 0); stageB(0, 0, 0); stageB(0, 1, 0);

  f32x4 acc[8][4] = {};
  int cur = 0;
  const int NT = K >> 6;
  for (int kt = 0; kt < NT; ++kt) {
    const char* Ab = smem + cur * 65536;
    const char* Bb = smem + cur * 65536 + 32768;
#pragma unroll
    for (int p = 0; p < 4; ++p) {
      const int mg = p & 1, ks = p >> 1;
      if (p == 0) { asm volatile("s_waitcnt vmcnt(0)" ::: "memory"); }
      BARRIER();
      if (kt + 1 < NT) {
        if (p == 0)      { stageA(cur ^ 1, 0, (kt + 1) << 6); stageA(cur ^ 1, 1, (kt + 1) << 6); }
        else if (p == 1) { stageB(cur ^ 1, 0, (kt + 1) << 6); }
        else if (p == 2) { stageB(cur ^ 1, 1, (kt + 1) << 6); }
      }
      bf16x8 af[4], bfr[4];
#pragma unroll
      for (int t = 0; t < 4; ++t) {
        const int Ra = wm * 128 + mg * 64 + t * 16 + fr;
        af[t] = *(const bf16x8*)(Ab + Ra * 128 + ((ks * 64 + kg * 16) ^ twistL));
        const int Rb = wn * 64 + t * 16 + fr;
        bfr[t] = *(const bf16x8*)(Bb + Rb * 128 + ((ks * 64 + kg * 16) ^ twistL));
      }
      asm volatile("s_waitcnt lgkmcnt(0)" ::: "memory");
      __builtin_amdgcn_sched_barrier(0);
      __builtin_amdgcn_s_setprio(1);
#pragma unroll
      for (int t = 0; t < 4; ++t)
#pragma unroll
        for (int nf = 0; nf < 4; ++nf)
          acc[mg * 4 + t][nf] = __builtin_amdgcn_mfma_f32_16x16x32_bf16(af[t], bfr[nf], acc[mg * 4 + t][nf], 0, 0, 0);
      __builtin_amdgcn_s_setprio(0);
    }
    cur ^= 1;
  }

#pragma unroll
  for (int mf = 0; mf < 8; ++mf)
#pragma unroll
    for (int nf = 0; nf < 4; ++nf) {
      const int col = n0 + wn * 64 + nf * 16 + fr;
#pragma unroll
      for (int r = 0; r < 4; ++r) {
        const int row = m0 + wm * 128 + mf * 16 + kg * 4 + r;
        float rsv = rsqrtf(sums[row] * (1.0f / HIDN) + 1e-6f);
        OUT[(size_t)row * N + col] = acc[mf][nf][r] * rsv;
      }
    }
}

// --- grouped causal conv as MFMA GEMM; epilogue: (Bc+bias)*dt -> dBt[row][l] --
__global__ __launch_bounds__(256) void conv_k(const unsigned short* __restrict__ xb,
                                              const unsigned short* __restrict__ wreT,
                                              const float* __restrict__ conv_b,
                                              const float* __restrict__ dt,
                                              float* __restrict__ dBt) {
  __shared__ __align__(16) unsigned short x_lds[67 * 64];
  const int l0 = blockIdx.x * 64, g = blockIdx.y, b = blockIdx.z;
  const int tid = threadIdx.x, lane = tid & 63, wid = tid >> 6;
  {
    const int r = tid >> 3, ch = (tid & 7) * 8;
#pragma unroll
    for (int pass = 0; pass < 3; ++pass) {
      int rr = r + pass * 32;
      if (rr < 67) {
        int lg = l0 - 3 + rr;
        bf16x8 v = {};
        if (lg >= 0) v = *(const bf16x8*)&xb[(size_t)(b * L_SEQ + lg) * HIDN + g * 64 + ch];
        *(bf16x8*)&x_lds[rr * 64 + ch] = v;
      }
    }
  }
  __syncthreads();
  const int fr = lane & 15, kg = lane >> 4, wm = wid;
  f32x4 acc[4] = {};
#pragma unroll
  for (int ks = 0; ks < 8; ++ks) {
    bf16x8 a = *(const bf16x8*)&x_lds[(wm * 16 + fr + (ks >> 1)) * 64 + (ks & 1) * 32 + kg * 8];
#pragma unroll
    for (int nt = 0; nt < 4; ++nt) {
      bf16x8 bq = *(const bf16x8*)&wreT[(size_t)(g * 64 + nt * 16 + fr) * 256 + ks * 32 + kg * 8];
      acc[nt] = __builtin_amdgcn_mfma_f32_16x16x32_bf16(a, bq, acc[nt], 0, 0, 0);
    }
  }
  const int lgb = l0 + wm * 16 + kg * 4;
  const float4 dt4 = *(const float4*)&dt[b * L_SEQ + lgb];
#pragma unroll
  for (int nt = 0; nt < 4; ++nt) {
    const int o = nt * 16 + fr;
    const float bias = conv_b[g * 64 + o];
    float4 vv;
    vv.x = (acc[nt][0] + bias) * dt4.x;
    vv.y = (acc[nt][1] + bias) * dt4.y;
    vv.z = (acc[nt][2] + bias) * dt4.z;
    vv.w = (acc[nt][3] + bias) * dt4.w;
    *(float4*)&dBt[((size_t)(b * NH + g) * 64 + o) * L_SEQ + lgb] = vv;
  }
}

// ==== FUSED: blocks 0..127 = chunked scan (1 wave; 128KB LDS -> CU-exclusive);
// ==== blocks 128..383 = gate GEMM 256^2 (silu -> bf16).
__global__ __launch_bounds__(512, 1) void scan_gate_k(const float* __restrict__ dBt,
                                                      const float* __restrict__ Aw,
                                                      const float* __restrict__ dt,
                                                      unsigned short* __restrict__ states,
                                                      const unsigned short* __restrict__ X,
                                                      const unsigned short* __restrict__ W,
                                                      unsigned short* __restrict__ GOUT) {
  __shared__ __align__(16) char smem[131072];
  if (blockIdx.x >= 128) {
    // ------------------ gate GEMM (M=8192,N=2048,K=2048) ---------------------
    const int tid = threadIdx.x, lane = tid & 63, w = tid >> 6;
    const int wm = w >> 2, wn = w & 3, fr = lane & 15, kg = lane >> 4;
    const int gb = blockIdx.x - 128;            // 0..255
    const int swz = (gb & 7) * 32 + (gb >> 3);  // XCD-bijective (256 blocks)
    const int m0 = (swz & 31) * 256, n0 = (swz >> 5) * 256;
    const int twistL = (fr & 7) << 4;
    auto stageA = [&](int buf, int half, int kq) {
#pragma unroll
      for (int q = 0; q < 2; ++q) {
        int s = q * 8192 + tid * 16;
        int r = s >> 7, cb = s & 127;
        const void* src = &X[(size_t)(m0 + half * 128 + r) * 2048 + kq + ((cb ^ ((r & 7) << 4)) >> 1)];
        void* dst = smem + buf * 65536 + half * 16384 + q * 8192 + w * 1024;
        gl_lds16(src, dst);
      }
    };
    auto stageB = [&](int buf, int half, int kq) {
#pragma unroll
      for (int q = 0; q < 2; ++q) {
        int s = q * 8192 + tid * 16;
        int r = s >> 7, cb = s & 127;
        const void* src = &W[(size_t)(n0 + half * 128 + r) * 2048 + kq + ((cb ^ ((r & 7) << 4)) >> 1)];
        void* dst = smem + buf * 65536 + 32768 + half * 16384 + q * 8192 + w * 1024;
        gl_lds16(src, dst);
      }
    };
    stageA(0, 0, 0); stageA(0, 1, 0); stageB(0, 0, 0); stageB(0, 1, 0);
    f32x4 acc[8][4] = {};
    int cur = 0;
    for (int kt = 0; kt < 32; ++kt) {
      const char* Ab = smem + cur * 65536;
      const char* Bb = smem + cur * 65536 + 32768;
#pragma unroll
      for (int p = 0; p < 4; ++p) {
        const int mg = p & 1, ks = p >> 1;
        if (p == 0) { asm volatile("s_waitcnt vmcnt(0)" ::: "memory"); }
        BARRIER();
        if (kt + 1 < 32) {
          if (p == 0)      { stageA(cur ^ 1, 0, (kt + 1) << 6); stageA(cur ^ 1, 1, (kt + 1) << 6); }
          else if (p == 1) { stageB(cur ^ 1, 0, (kt + 1) << 6); }
          else if (p == 2) { stageB(cur ^ 1, 1, (kt + 1) << 6); }
        }
        bf16x8 af[4], bfr[4];
#pragma unroll
        for (int t = 0; t < 4; ++t) {
          const int Ra = wm * 128 + mg * 64 + t * 16 + fr;
          af[t] = *(const bf16x8*)(Ab + Ra * 128 + ((ks * 64 + kg * 16) ^ twistL));
          const int Rb = wn * 64 + t * 16 + fr;
          bfr[t] = *(const bf16x8*)(Bb + Rb * 128 + ((ks * 64 + kg * 16) ^ twistL));
        }
        asm volatile("s_waitcnt lgkmcnt(0)" ::: "memory");
        __builtin_amdgcn_sched_barrier(0);
        __builtin_amdgcn_s_setprio(1);
#pragma unroll
        for (int t = 0; t < 4; ++t)
#pragma unroll
          for (int nf = 0; nf < 4; ++nf)
            acc[mg * 4 + t][nf] = __builtin_amdgcn_mfma_f32_16x16x32_bf16(af[t], bfr[nf], acc[mg * 4 + t][nf], 0, 0, 0);
        __builtin_amdgcn_s_setprio(0);
      }
      cur ^= 1;
    }
#pragma unroll
    for (int mf = 0; mf < 8; ++mf)
#pragma unroll
      for (int nf = 0; nf < 4; ++nf) {
        const int col = n0 + wn * 64 + nf * 16 + fr;
#pragma unroll
        for (int r = 0; r < 4; ++r) {
          const int row = m0 + wm * 128 + mf * 16 + kg * 4 + r;
          float v = acc[mf][nf][r];
          v = v / (1.f + __expf(-v));
          GOUT[(size_t)row * 2048 + col] = f2bf(v);
        }
      }
    return;
  }
  // ----------------------------- scan (1 wave) ------------------------------
  if (threadIdx.x >= 64) return;
  const int bid = blockIdx.x;          // b*32 + h
  const int h = bid & 31, b = bid >> 5;
  const int lane = threadIdx.x;
  const int fr = lane & 15, kg = lane >> 4;

  char* sp = smem;                 // s-pairs [CHUNK] stride 176B   (11264 B)
  char* xT = smem + 11264;         // xT [CHUNK] stride 304B        (19456 B)
  char* db = smem + 30720;         // Dv staging: 2 bufs x 16KB

  bf16x8 afr[4][2];
  {
    const float* Ah = Aw + (size_t)h * 64 * 64;
#pragma unroll
    for (int mb = 0; mb < 4; ++mb)
#pragma unroll
      for (int kt = 0; kt < 2; ++kt) {
        const float* p = &Ah[(size_t)(mb * 16 + fr) * 64 + kt * 32 + kg * 8];
        float4 v0 = *(const float4*)p;
        float4 v1 = *(const float4*)(p + 4);
        bf16x8 f;
        f[0] = (short)f2bf(v0.x); f[1] = (short)f2bf(v0.y);
        f[2] = (short)f2bf(v0.z); f[3] = (short)f2bf(v0.w);
        f[4] = (short)f2bf(v1.x); f[5] = (short)f2bf(v1.y);
        f[6] = (short)f2bf(v1.z); f[7] = (short)f2bf(v1.w);
        afr[mb][kt] = f;
      }
  }

  const float* dBp = dBt + (size_t)(bid * 64 + lane) * L_SEQ;   // own row
  unsigned short* stbase = states + (size_t)bid * L_SEQ * 64;
  const float* dtp = dt + b * L_SEQ;
  const int spw = (lane >> 1) * 4;

  auto pfDv = [&](int buf, int c) {
#pragma unroll
    for (int q = 0; q < 16; ++q)
      gl_lds16(&dBp[c * CHUNK + q * 4], db + buf * 16384 + q * 1024);
  };
  pfDv(0, 0);

  float scs = 0.f;
  for (int c = 0; c < L_SEQ / CHUNK; ++c) {
    const int l0 = c * CHUNK;
    const int buf = c & 1;
    if (c == 0) { asm volatile("s_waitcnt vmcnt(0)" ::: "memory"); }
    else        { asm volatile("s_waitcnt vmcnt(8)" ::: "memory"); }
    float Dv[CHUNK];
#pragma unroll
    for (int q = 0; q < 16; ++q) {
      f32x4 v = *(const f32x4*)(db + buf * 16384 + q * 1024 + lane * 16);
      Dv[q * 4] = v[0]; Dv[q * 4 + 1] = v[1]; Dv[q * 4 + 2] = v[2]; Dv[q * 4 + 3] = v[3];
    }
    float dtq[4];
#pragma unroll
    for (int tb = 0; tb < 4; ++tb) dtq[tb] = dtp[l0 + tb * 16 + fr];
    if (c + 1 < L_SEQ / CHUNK) pfDv(buf ^ 1, c + 1);

    // ---- pass 1 (E=1): write s-pair (state BEFORE step l), then s += Dv ----
    {
      float s = scs;
#pragma unroll
      for (int l = 0; l < CHUNK; ++l) {
        float sn = qperm<0xB1>(s);
        float lo = (lane & 1) ? sn : s;
        float hi = (lane & 1) ? s : sn;
        unsigned pw;
        asm("v_cvt_pk_bf16_f32 %0, %1, %2" : "=v"(pw) : "v"(lo), "v"(hi));
        *(unsigned*)(sp + l * 176 + spw) = pw;
        s = s + Dv[l];
      }
    }
    asm volatile("" ::: "memory");
    // ---- batched matvec: X[m][t] = A_w · S, scaled by dt ----
    {
      bf16x8 bf[4][2];
#pragma unroll
      for (int tb = 0; tb < 4; ++tb)
#pragma unroll
        for (int kt = 0; kt < 2; ++kt)
          bf[tb][kt] = *(const bf16x8*)(sp + (tb * 16 + fr) * 176 + (kt * 16 + kg * 4) * 4);
      f32x4 acc[4][4];
#pragma unroll
      for (int mb = 0; mb < 4; ++mb)
#pragma unroll
        for (int tb = 0; tb < 4; ++tb) {
          f32x4 z = {0.f, 0.f, 0.f, 0.f};
          f32x4 t0 = __builtin_amdgcn_mfma_f32_16x16x32_bf16(afr[mb][0], bf[tb][0], z, 0, 0, 0);
          acc[mb][tb] = __builtin_amdgcn_mfma_f32_16x16x32_bf16(afr[mb][1], bf[tb][1], t0, 0, 0, 0);
        }
#pragma unroll
      for (int mb = 0; mb < 4; ++mb)
#pragma unroll
        for (int tb = 0; tb < 4; ++tb) {
          f32x4 v = acc[mb][tb];
          v[0] *= dtq[tb]; v[1] *= dtq[tb]; v[2] *= dtq[tb]; v[3] *= dtq[tb];
          *(f32x4*)(xT + (tb * 16 + fr) * 304 + (mb * 16 + kg * 4) * 4) = v;
        }
    }
    asm volatile("" ::: "memory");
    // ---- final pass: E inline; pack exact states to sp; bulk-store chunk ----
    {
      float s = scs;
#pragma unroll
      for (int gq = 0; gq < CHUNK / 8; ++gq) {
        float xs[8];
#pragma unroll
        for (int j = 0; j < 8; ++j)
          xs[j] = *(const float*)(xT + (gq * 8 + j) * 304 + lane * 4);
#pragma unroll
        for (int j = 0; j < 8; ++j) {
          const int l = gq * 8 + j;
          float xv = xs[j];
          float E = __builtin_fmaf(xv * xv, 0.5f, 1.0f + xv);
          s = __builtin_fmaf(E, s, Dv[l]);
          float sn = qperm<0xB1>(s);
          float lo = (lane & 1) ? sn : s;
          float hi = (lane & 1) ? s : sn;
          unsigned pw;
          asm("v_cvt_pk_bf16_f32 %0, %1, %2" : "=v"(pw) : "v"(lo), "v"(hi));
          *(unsigned*)(sp + l * 176 + spw) = pw;
        }
      }
      scs = s;
    }
    asm volatile("" ::: "memory");
    // 8 coalesced 16B stores replace 64 scattered 2B stores
#pragma unroll
    for (int j2 = 0; j2 < 8; ++j2) {
      const int g0 = j2 * 1024 + lane * 16;          // byte within chunk block
      const int lrow = g0 >> 7, cbyte = g0 & 127;
      bf16x8 vv = *(const bf16x8*)(sp + lrow * 176 + cbyte);
      *(bf16x8*)&stbase[(size_t)l0 * 64 + (g0 >> 1)] = vv;
    }
  }
}

// -- C proj + x*D + silu(gate); LDS-staged coalesced bf16 stores + row sums ----
__global__ __launch_bounds__(256) void proj_k(const unsigned short* __restrict__ st,
                                              const unsigned short* __restrict__ cwb,
                                              const unsigned short* __restrict__ xbp,
                                              const float* __restrict__ Dp,
                                              const unsigned short* __restrict__ gsb,
                                              unsigned short* __restrict__ hsb,
                                              float* __restrict__ sums) {
  __shared__ __align__(16) unsigned short hls[64 * 72];   // padded stride 72
  const int l0 = blockIdx.x * 64, h = blockIdx.y, b = blockIdx.z;
  const int tid = threadIdx.x, lane = tid & 63, wid = tid >> 6;
  const int fr = lane & 15, kg = lane >> 4, wm = wid;
  f32x4 acc[4] = {};
#pragma unroll
  for (int ks = 0; ks < 2; ++ks) {
    bf16x8 a = *(const bf16x8*)&st[((size_t)(b * NH + h) * L_SEQ + l0 + wm * 16 + fr) * 64 + ks * 32 + kg * 8];
#pragma unroll
    for (int nt = 0; nt < 4; ++nt) {
      bf16x8 bq = *(const bf16x8*)&cwb[(size_t)(h * 64 + nt * 16 + fr) * 64 + ks * 32 + kg * 8];
      acc[nt] = __builtin_amdgcn_mfma_f32_16x16x32_bf16(a, bq, acc[nt], 0, 0, 0);
    }
  }
  const float Dh = Dp[h];
#pragma unroll
  for (int r = 0; r < 4; ++r) {
    const int lg = l0 + wm * 16 + kg * 4 + r;
    float sq = 0.f;
#pragma unroll
    for (int nt = 0; nt < 4; ++nt) {
      const int ccol = h * 64 + nt * 16 + fr;
      const size_t idx = (size_t)(b * L_SEQ + lg) * HIDN + ccol;
      float v = acc[nt][r] + bf2f(xbp[idx]) * Dh;
      float hv = v * bf2f(gsb[idx]);
      hls[(wm * 16 + kg * 4 + r) * 72 + nt * 16 + fr] = f2bf(hv);
      sq += hv * hv;
    }
    sq += __shfl_xor(sq, 1);
    sq += __shfl_xor(sq, 2);
    sq += __shfl_xor(sq, 4);
    sq += __shfl_xor(sq, 8);
    if (fr == 0) atomicAdd(&sums[b * L_SEQ + lg], sq);
  }
  __syncthreads();
#pragma unroll
  for (int it = 0; it < 2; ++it) {
    int unit = tid + it * 256;               // 512 units of 16B
    int row = unit >> 3, seg = unit & 7;
    bf16x8 vv = *(const bf16x8*)&hls[row * 72 + seg * 8];
    *(bf16x8*)&hsb[(size_t)(b * L_SEQ + l0 + row) * HIDN + h * 64 + seg * 8] = vv;
  }
}

extern "C" void kernel_launch(void* const* d_in, const int* in_sizes, int n_in,
                              void* d_out, int out_size, void* d_ws, size_t ws_size,
                              hipStream_t stream) {
  const float* x  = (const float*)d_in[0];
  const float* dt = (const float*)d_in[1];
  const float* gw = (const float*)d_in[2];
  const float* Aw = (const float*)d_in[3];
  const float* cw = (const float*)d_in[4];
  const float* cb = (const float*)d_in[5];
  const float* Cw = (const float*)d_in[6];
  const float* Dp = (const float*)d_in[7];
  const float* nw = (const float*)d_in[8];
  const float* ow = (const float*)d_in[9];
  float* out = (float*)d_out;

  // workspace (bytes): hsb overlays dBt (dead after scan); stb has own slot.
  // gate bf16 lives in d_out's first 32MB (dead before out-GEMM writes).
  char* w = (char*)d_ws;
  unsigned short* xb   = (unsigned short*)(w);                // 32MB
  unsigned short* gwb  = (unsigned short*)(w + 33554432);     // 8MB
  unsigned short* owb  = (unsigned short*)(w + 41943040);     // 8MB (ow*nw)
  unsigned short* wret = (unsigned short*)(w + 50331648);     // 1MB
  unsigned short* cwb  = (unsigned short*)(w + 51380224);     // 256KB
  float*          sums = (float*)(w + 51642368);              // 32KB (row sums)
  float*          dBt  = (float*)(w + 52428800);              // 64MB
  unsigned short* hsb  = (unsigned short*)(w + 52428800);     // overlay (after scan)
  unsigned short* stb  = (unsigned short*)(w + 119537664);    // 32MB
  unsigned short* gsb  = (unsigned short*)d_out;              // gate bf16, 32MB
  if (ws_size < 153092096) return;

  hipMemsetAsync(sums, 0, 8192 * sizeof(float), stream);
  prep_k<<<2048, 256, 0, stream>>>(x, gw, ow, nw, Cw, cw, xb, gwb, owb, cwb, wret);
  conv_k<<<dim3(32, 32, 4), 256, 0, stream>>>(xb, wret, cb, dt, dBt);
  // FUSED: scan (blocks 0..127, CU-exclusive via 128KB LDS) || gate GEMM
  scan_gate_k<<<384, 512, 0, stream>>>(dBt, Aw, dt, stb, xb, gwb, gsb);
  proj_k<<<dim3(32, 32, 4), 256, 0, stream>>>(stb, cwb, xb, Dp, gsb, hsb, sums);
  gemm256_out_k<<<256, 512, 0, stream>>>(hsb, owb, sums, out, 8192, 2048, 2048);
}